// Round 2
// baseline (760.114 us; speedup 1.0000x reference)
//
#include <hip/hip_runtime.h>

// GTN_MultiHeadAttention: B=8,S=1024,D=512,H=8,hd=64, N=H*B=64 head-batches.
// Round 2: fp32 I/O (reference dtypes are authoritative; R1's bf16-I/O guess
// produced NaN from decoding fp32 mantissa halves as bf16).
// Correctness-first fp32-compute pipeline, 5 kernels. MFMA comes next round.

typedef unsigned short u16;
typedef unsigned int u32;

// ---------------- K1: QKV projection ----------------
// y = x @ W + b for W in {Wq,Wk,Wv}; write split-heads layout [n=h*8+b][s][64], fp32.
// grid (8 colTiles, 128 rowTiles, 3 weights), block 256
__global__ __launch_bounds__(256) void k_qkv(
    const float* __restrict__ x,
    const float* __restrict__ Wq, const float* __restrict__ bq,
    const float* __restrict__ Wk, const float* __restrict__ bk,
    const float* __restrict__ Wv, const float* __restrict__ bv,
    float* __restrict__ qo, float* __restrict__ ko, float* __restrict__ vo)
{
    const int which = blockIdx.z;
    const float* __restrict__ W  = (which == 0) ? Wq : (which == 1) ? Wk : Wv;
    const float* __restrict__ bi = (which == 0) ? bq : (which == 1) ? bk : bv;
    float* __restrict__ out      = (which == 0) ? qo : (which == 1) ? ko : vo;

    const int h = blockIdx.x;            // head index (colTile = h*64)
    const int colTile = h * 64;
    const int rowTile = blockIdx.y * 64;

    __shared__ __align__(16) float As[16][68];  // As[kk][row]
    __shared__ __align__(16) float Bs[16][68];  // Bs[kk][col]

    const int tid = threadIdx.x;
    const int tx = tid & 15, ty = tid >> 4;     // 16x16 thread grid, 4x4 micro-tile
    const int li = tid >> 2, lq = tid & 3;      // loader: row 0..63, quad 0..3

    float acc[4][4] = {};

    for (int k0 = 0; k0 < 512; k0 += 16) {
        float4 av  = *(const float4*)&x[(size_t)(rowTile + li) * 512 + k0 + lq * 4];
        float4 bvv = *(const float4*)&W[(size_t)(k0 + ty) * 512 + colTile + tx * 4];
        __syncthreads();
        As[lq * 4 + 0][li] = av.x;
        As[lq * 4 + 1][li] = av.y;
        As[lq * 4 + 2][li] = av.z;
        As[lq * 4 + 3][li] = av.w;
        Bs[ty][tx * 4 + 0] = bvv.x;
        Bs[ty][tx * 4 + 1] = bvv.y;
        Bs[ty][tx * 4 + 2] = bvv.z;
        Bs[ty][tx * 4 + 3] = bvv.w;
        __syncthreads();
        #pragma unroll
        for (int kk = 0; kk < 16; ++kk) {
            float4 a4 = *(const float4*)&As[kk][ty * 4];
            float4 b4 = *(const float4*)&Bs[kk][tx * 4];
            float aa[4] = {a4.x, a4.y, a4.z, a4.w};
            float bb[4] = {b4.x, b4.y, b4.z, b4.w};
            #pragma unroll
            for (int i = 0; i < 4; ++i)
                #pragma unroll
                for (int j = 0; j < 4; ++j)
                    acc[i][j] = fmaf(aa[i], bb[j], acc[i][j]);
        }
    }

    float biasv[4];
    #pragma unroll
    for (int j = 0; j < 4; ++j) biasv[j] = bi[colTile + tx * 4 + j];
    #pragma unroll
    for (int i = 0; i < 4; ++i) {
        const int r = rowTile + ty * 4 + i;
        const int b = r >> 10, s = r & 1023;
        float4 o;
        o.x = acc[i][0] + biasv[0];
        o.y = acc[i][1] + biasv[1];
        o.z = acc[i][2] + biasv[2];
        o.w = acc[i][3] + biasv[3];
        // n = h*8 + b  (split_heads: reshape->transpose(2,0,1,3))
        *(float4*)&out[(size_t)(((h * 8 + b) * 1024) + s) * 64 + tx * 4] = o;
    }
}

// ---------------- K2: scores = q @ k^T, write raw heatmap (fp32) ----------------
// grid (16 tTiles, 16 sTiles, 64 n), block 256
__global__ __launch_bounds__(256) void k_scores(
    const float* __restrict__ q, const float* __restrict__ k, float* __restrict__ heat)
{
    const int n = blockIdx.z;
    const int tTile = blockIdx.x * 64;
    const int sTile = blockIdx.y * 64;

    __shared__ __align__(16) float As[16][68];  // As[kk][s-row]
    __shared__ __align__(16) float Bs[16][68];  // Bs[kk][t-col]

    const int tid = threadIdx.x;
    const int tx = tid & 15, ty = tid >> 4;
    const int li = tid >> 2, lq = tid & 3;

    const float* __restrict__ qn = q + (size_t)n * 1024 * 64;
    const float* __restrict__ kn = k + (size_t)n * 1024 * 64;

    float acc[4][4] = {};

    for (int k0 = 0; k0 < 64; k0 += 16) {
        float4 av  = *(const float4*)&qn[(size_t)(sTile + li) * 64 + k0 + lq * 4];
        float4 bvv = *(const float4*)&kn[(size_t)(tTile + li) * 64 + k0 + lq * 4];
        __syncthreads();
        As[lq * 4 + 0][li] = av.x;
        As[lq * 4 + 1][li] = av.y;
        As[lq * 4 + 2][li] = av.z;
        As[lq * 4 + 3][li] = av.w;
        Bs[lq * 4 + 0][li] = bvv.x;
        Bs[lq * 4 + 1][li] = bvv.y;
        Bs[lq * 4 + 2][li] = bvv.z;
        Bs[lq * 4 + 3][li] = bvv.w;
        __syncthreads();
        #pragma unroll
        for (int kk = 0; kk < 16; ++kk) {
            float4 a4 = *(const float4*)&As[kk][ty * 4];
            float4 b4 = *(const float4*)&Bs[kk][tx * 4];
            float aa[4] = {a4.x, a4.y, a4.z, a4.w};
            float bb[4] = {b4.x, b4.y, b4.z, b4.w};
            #pragma unroll
            for (int i = 0; i < 4; ++i)
                #pragma unroll
                for (int j = 0; j < 4; ++j)
                    acc[i][j] = fmaf(aa[i], bb[j], acc[i][j]);
        }
    }

    float* __restrict__ hp = heat + ((size_t)n << 20);
    #pragma unroll
    for (int i = 0; i < 4; ++i) {
        float4 o;
        o.x = acc[i][0];
        o.y = acc[i][1];
        o.z = acc[i][2];
        o.w = acc[i][3];
        *(float4*)&hp[(size_t)(sTile + ty * 4 + i) * 1024 + tTile + tx * 4] = o;
    }
}

// ---------------- K3: per-row causal softmax stats (m, 1/l) ----------------
// one wave per row; block 256 = 4 rows; grid 16384
__global__ __launch_bounds__(256) void k_stats(const float* __restrict__ heat,
    float* __restrict__ mb, float* __restrict__ lb)
{
    const int row = blockIdx.x * 4 + (threadIdx.x >> 6);
    const int lane = threadIdx.x & 63;
    const int n = row >> 10, s = row & 1023;
    const float* __restrict__ rp = heat + ((size_t)n << 20) + ((size_t)s << 10);

    float mx = -3.0e38f;
    for (int t = lane * 4; t <= s; t += 256) {
        float4 fv = *(const float4*)&rp[t];
        if (t + 0 <= s) mx = fmaxf(mx, fv.x);
        if (t + 1 <= s) mx = fmaxf(mx, fv.y);
        if (t + 2 <= s) mx = fmaxf(mx, fv.z);
        if (t + 3 <= s) mx = fmaxf(mx, fv.w);
    }
    #pragma unroll
    for (int o = 32; o > 0; o >>= 1) mx = fmaxf(mx, __shfl_xor(mx, o));

    float l = 0.f;
    for (int t = lane * 4; t <= s; t += 256) {
        float4 fv = *(const float4*)&rp[t];
        if (t + 0 <= s) l += __expf(fv.x - mx);
        if (t + 1 <= s) l += __expf(fv.y - mx);
        if (t + 2 <= s) l += __expf(fv.z - mx);
        if (t + 3 <= s) l += __expf(fv.w - mx);
    }
    #pragma unroll
    for (int o = 32; o > 0; o >>= 1) l += __shfl_xor(l, o);

    if (lane == 0) { mb[row] = mx; lb[row] = 1.0f / l; }
}

// ---------------- K4: wv = softmax(scores) @ v ----------------
// grid (16 sTiles, 64 n), block 256; causal early-exit on k-loop
__global__ __launch_bounds__(256) void k_pv(const float* __restrict__ heat,
    const float* __restrict__ v, const float* __restrict__ mb, const float* __restrict__ lb,
    float* __restrict__ wv)
{
    const int n = blockIdx.y;
    const int sTile = blockIdx.x * 64;

    __shared__ __align__(16) float As[16][68];  // P[kk(t)][s-row]
    __shared__ __align__(16) float Vs[16][68];  // V[kk(t)][hd]
    __shared__ float rm[64], rli[64];

    const int tid = threadIdx.x;
    const int tx = tid & 15, ty = tid >> 4;
    const int li = tid >> 2, lq = tid & 3;

    if (tid < 64) {
        rm[tid]  = mb[(n << 10) + sTile + tid];
        rli[tid] = lb[(n << 10) + sTile + tid];
    }
    __syncthreads();

    const float* __restrict__ hp = heat + ((size_t)n << 20);
    const float* __restrict__ vn = v + (size_t)n * 1024 * 64;

    float acc[4][4] = {};
    const int kmax = sTile + 64;  // only t < sTile+64 contributes (causal)

    for (int t0 = 0; t0 < kmax; t0 += 16) {
        float4 fv = *(const float4*)&hp[(size_t)(sTile + li) * 1024 + t0 + lq * 4];
        float4 vv = *(const float4*)&vn[(size_t)(t0 + ty) * 64 + tx * 4];
        const int srow = sTile + li;
        const float m_i = rm[li], l_i = rli[li];
        float p[4];
        {
            float f[4] = {fv.x, fv.y, fv.z, fv.w};
            #pragma unroll
            for (int j = 0; j < 4; ++j) {
                const int t = t0 + lq * 4 + j;
                p[j] = (t <= srow) ? __expf(f[j] - m_i) * l_i : 0.f;
            }
        }
        __syncthreads();
        As[lq * 4 + 0][li] = p[0];
        As[lq * 4 + 1][li] = p[1];
        As[lq * 4 + 2][li] = p[2];
        As[lq * 4 + 3][li] = p[3];
        Vs[ty][tx * 4 + 0] = vv.x;
        Vs[ty][tx * 4 + 1] = vv.y;
        Vs[ty][tx * 4 + 2] = vv.z;
        Vs[ty][tx * 4 + 3] = vv.w;
        __syncthreads();
        #pragma unroll
        for (int kk = 0; kk < 16; ++kk) {
            float4 a4 = *(const float4*)&As[kk][ty * 4];
            float4 b4 = *(const float4*)&Vs[kk][tx * 4];
            float aa[4] = {a4.x, a4.y, a4.z, a4.w};
            float bb[4] = {b4.x, b4.y, b4.z, b4.w};
            #pragma unroll
            for (int i = 0; i < 4; ++i)
                #pragma unroll
                for (int j = 0; j < 4; ++j)
                    acc[i][j] = fmaf(aa[i], bb[j], acc[i][j]);
        }
    }

    #pragma unroll
    for (int i = 0; i < 4; ++i) {
        float4 o;
        o.x = acc[i][0];
        o.y = acc[i][1];
        o.z = acc[i][2];
        o.w = acc[i][3];
        *(float4*)&wv[(size_t)((n << 10) + sTile + ty * 4 + i) * 64 + tx * 4] = o;
    }
}

// ---------------- K5: out = concat_heads(wv) @ Wo + bo ----------------
// grid (8 colTiles, 128 rowTiles), block 256
__global__ __launch_bounds__(256) void k_out(const float* __restrict__ wv,
    const float* __restrict__ Wo, const float* __restrict__ bo, float* __restrict__ out)
{
    const int colTile = blockIdx.x * 64;
    const int rowTile = blockIdx.y * 64;

    __shared__ __align__(16) float As[16][68];
    __shared__ __align__(16) float Bs[16][68];

    const int tid = threadIdx.x;
    const int tx = tid & 15, ty = tid >> 4;
    const int li = tid >> 2, lq = tid & 3;

    const int r = rowTile + li;
    const int b = r >> 10, s = r & 1023;

    float acc[4][4] = {};

    for (int k0 = 0; k0 < 512; k0 += 16) {
        // gather A: column c = h*64+hd maps to wv[(h*8+b)][s][hd]
        const int h = k0 >> 6;
        const int hd0 = (k0 & 63) + lq * 4;  // stays within one h for a 16-chunk
        float4 av = *(const float4*)&wv[(size_t)(((h * 8 + b) * 1024) + s) * 64 + hd0];
        float4 bu = *(const float4*)&Wo[(size_t)(k0 + ty) * 512 + colTile + tx * 4];
        __syncthreads();
        As[lq * 4 + 0][li] = av.x;
        As[lq * 4 + 1][li] = av.y;
        As[lq * 4 + 2][li] = av.z;
        As[lq * 4 + 3][li] = av.w;
        Bs[ty][tx * 4 + 0] = bu.x;
        Bs[ty][tx * 4 + 1] = bu.y;
        Bs[ty][tx * 4 + 2] = bu.z;
        Bs[ty][tx * 4 + 3] = bu.w;
        __syncthreads();
        #pragma unroll
        for (int kk = 0; kk < 16; ++kk) {
            float4 a4 = *(const float4*)&As[kk][ty * 4];
            float4 b4 = *(const float4*)&Bs[kk][tx * 4];
            float aa[4] = {a4.x, a4.y, a4.z, a4.w};
            float bb[4] = {b4.x, b4.y, b4.z, b4.w};
            #pragma unroll
            for (int i = 0; i < 4; ++i)
                #pragma unroll
                for (int j = 0; j < 4; ++j)
                    acc[i][j] = fmaf(aa[i], bb[j], acc[i][j]);
        }
    }

    float biasv[4];
    #pragma unroll
    for (int j = 0; j < 4; ++j) biasv[j] = bo[colTile + tx * 4 + j];
    #pragma unroll
    for (int i = 0; i < 4; ++i) {
        const int r2 = rowTile + ty * 4 + i;
        float4 o;
        o.x = acc[i][0] + biasv[0];
        o.y = acc[i][1] + biasv[1];
        o.z = acc[i][2] + biasv[2];
        o.w = acc[i][3] + biasv[3];
        *(float4*)&out[(size_t)r2 * 512 + colTile + tx * 4] = o;
    }
}

extern "C" void kernel_launch(void* const* d_in, const int* in_sizes, int n_in,
                              void* d_out, int out_size, void* d_ws, size_t ws_size,
                              hipStream_t stream)
{
    (void)in_sizes; (void)n_in; (void)out_size; (void)ws_size;

    const float* x  = (const float*)d_in[0];
    const float* Wq = (const float*)d_in[1];
    const float* bq = (const float*)d_in[2];
    const float* Wk = (const float*)d_in[3];
    const float* bk = (const float*)d_in[4];
    const float* Wv = (const float*)d_in[5];
    const float* bv = (const float*)d_in[6];
    const float* Wo = (const float*)d_in[7];
    const float* bo = (const float*)d_in[8];

    float* outp = (float*)d_out;             // [8,1024,512] fp32
    float* heat = outp + 4194304;            // [64,1024,1024] fp32

    // workspace: fp32 q,k,v,wv [64,1024,64] + m,l [64*1024]  (~67.6 MB)
    float* ws  = (float*)d_ws;
    float* qb  = ws;
    float* kb  = qb  + 4194304;
    float* vb  = kb  + 4194304;
    float* wvb = vb  + 4194304;
    float* mb  = wvb + 4194304;
    float* lb  = mb  + 65536;

    k_qkv   <<<dim3(8, 128, 3), 256, 0, stream>>>(x, Wq, bq, Wk, bk, Wv, bv, qb, kb, vb);
    k_scores<<<dim3(16, 16, 64), 256, 0, stream>>>(qb, kb, heat);
    k_stats <<<dim3(16384), 256, 0, stream>>>(heat, mb, lb);
    k_pv    <<<dim3(16, 64), 256, 0, stream>>>(heat, vb, mb, lb, wvb);
    k_out   <<<dim3(8, 128), 256, 0, stream>>>(wvb, Wo, bo, outp);
}

// Round 3
// 568.837 us; speedup vs baseline: 1.3363x; 1.3363x over previous
//
#include <hip/hip_runtime.h>

// GTN_MultiHeadAttention: B=8,S=1024,D=512,H=8,hd=64, N=H*B=64.
// Round 3: bf16 MFMA everywhere (16x16x32_bf16), fp32 I/O.
// Layouts (verified, learn_hip m89/m120): A[m=lane&15][k=quad*8+j],
// B[k=quad*8+j][n=lane&15], C/D col=lane&15 row=quad*4+reg.
// LDS padded strides 72/136 elems (+4-bank row rotation -> <=2-way, free).

typedef unsigned short u16;
typedef unsigned int u32;
typedef __attribute__((ext_vector_type(8))) short bf8;   // 8 bf16 as shorts (16B)
typedef __attribute__((ext_vector_type(4))) float f4;

__device__ __forceinline__ u16 f2bf(float f) {
    u32 x = __builtin_bit_cast(u32, f);
    return (u16)((x + 0x7FFFu + ((x >> 16) & 1u)) >> 16);  // RNE
}

#define MFMA16(a, b, c) __builtin_amdgcn_mfma_f32_16x16x32_bf16((a), (b), (c), 0, 0, 0)

// ---------------- cvt: x fp32 -> bf16 (natural) ----------------
__global__ __launch_bounds__(256) void k_cvt_x(const float4* __restrict__ xi,
                                               ushort4* __restrict__ xo)
{
    int idx = blockIdx.x * 256 + threadIdx.x;
    for (int i = idx; i < 1048576; i += 262144) {
        float4 f = xi[i];
        ushort4 o;
        o.x = f2bf(f.x); o.y = f2bf(f.y); o.z = f2bf(f.z); o.w = f2bf(f.w);
        xo[i] = o;
    }
}

// ---------------- cvt: W fp32 [k][c] -> bf16 transposed [c][k] ----------------
// grid (8 kTiles, 8 cTiles, 4 weights), block 256, 64x64 tiles
__global__ __launch_bounds__(256) void k_cvt_wT(
    const float* __restrict__ Wq, const float* __restrict__ Wk,
    const float* __restrict__ Wv, const float* __restrict__ Wo,
    u16* __restrict__ WqT, u16* __restrict__ WkT,
    u16* __restrict__ WvT, u16* __restrict__ WoT)
{
    const int z = blockIdx.z;
    const float* __restrict__ W = (z == 0) ? Wq : (z == 1) ? Wk : (z == 2) ? Wv : Wo;
    u16* __restrict__ WT        = (z == 0) ? WqT : (z == 1) ? WkT : (z == 2) ? WvT : WoT;

    __shared__ __align__(16) u16 Ts[64 * 72];
    const int k0 = blockIdx.x * 64, c0 = blockIdx.y * 64;
    const int tid = threadIdx.x;
    const int r = tid >> 4, cc = (tid & 15) * 4;
    #pragma unroll
    for (int rr = r; rr < 64; rr += 16) {
        float4 f = *(const float4*)&W[(size_t)(k0 + rr) * 512 + c0 + cc];
        Ts[(cc + 0) * 72 + rr] = f2bf(f.x);
        Ts[(cc + 1) * 72 + rr] = f2bf(f.y);
        Ts[(cc + 2) * 72 + rr] = f2bf(f.z);
        Ts[(cc + 3) * 72 + rr] = f2bf(f.w);
    }
    __syncthreads();
    #pragma unroll
    for (int i = 0; i < 2; ++i) {
        int gi = tid + i * 256;
        int cr = gi >> 3, g = gi & 7;
        bf8 v = *(bf8*)&Ts[cr * 72 + g * 8];
        *(bf8*)&WT[(size_t)(c0 + cr) * 512 + k0 + g * 8] = v;
    }
}

// ---------------- K1: QKV projection, MFMA ----------------
// grid (4 colTiles, 64 rowTiles, 3 weights), block 256 (4 waves, 2x2)
__global__ __launch_bounds__(256) void k_qkv(
    const u16* __restrict__ xb,
    const u16* __restrict__ WqT, const u16* __restrict__ WkT, const u16* __restrict__ WvT,
    const float* __restrict__ bq, const float* __restrict__ bk, const float* __restrict__ bv,
    u16* __restrict__ qb, u16* __restrict__ kb, u16* __restrict__ vT)
{
    const int which = blockIdx.z;
    const u16* __restrict__ WT     = (which == 0) ? WqT : (which == 1) ? WkT : WvT;
    const float* __restrict__ bias = (which == 0) ? bq : (which == 1) ? bk : bv;

    const int colTile = blockIdx.x * 128;
    const int rowTile = blockIdx.y * 128;

    __shared__ __align__(16) u16 As[128 * 72];
    __shared__ __align__(16) u16 Bs[128 * 72];

    const int tid = threadIdx.x;
    const int lane = tid & 63, w = tid >> 6;
    const int lm = lane & 15, kq = lane >> 4;
    const int mB = (w >> 1) * 64, nB = (w & 1) * 64;

    f4 acc[4][4] = {};

    for (int k0 = 0; k0 < 512; k0 += 64) {
        __syncthreads();
        #pragma unroll
        for (int i = 0; i < 4; ++i) {
            int gi = tid + i * 256;
            int r = gi >> 3, c = gi & 7;
            *(bf8*)&As[r * 72 + c * 8] = *(const bf8*)&xb[(size_t)(rowTile + r) * 512 + k0 + c * 8];
            *(bf8*)&Bs[r * 72 + c * 8] = *(const bf8*)&WT[(size_t)(colTile + r) * 512 + k0 + c * 8];
        }
        __syncthreads();
        #pragma unroll
        for (int ks = 0; ks < 2; ++ks) {
            bf8 a[4], b[4];
            #pragma unroll
            for (int mi = 0; mi < 4; ++mi) a[mi] = *(bf8*)&As[(mB + mi * 16 + lm) * 72 + ks * 32 + kq * 8];
            #pragma unroll
            for (int ni = 0; ni < 4; ++ni) b[ni] = *(bf8*)&Bs[(nB + ni * 16 + lm) * 72 + ks * 32 + kq * 8];
            #pragma unroll
            for (int mi = 0; mi < 4; ++mi)
                #pragma unroll
                for (int ni = 0; ni < 4; ++ni)
                    acc[mi][ni] = MFMA16(a[mi], b[ni], acc[mi][ni]);
        }
    }

    if (which < 2) {
        u16* __restrict__ outp = (which == 0) ? qb : kb;
        #pragma unroll
        for (int mi = 0; mi < 4; ++mi) {
            const int r0 = rowTile + mB + mi * 16 + kq * 4;
            #pragma unroll
            for (int ni = 0; ni < 4; ++ni) {
                const int c = colTile + nB + ni * 16 + lm;
                const float bv_ = bias[c];
                const int h = c >> 6, hd = c & 63;
                #pragma unroll
                for (int rg = 0; rg < 4; ++rg) {
                    const int rr = r0 + rg;
                    const int b = rr >> 10, s = rr & 1023;
                    outp[(size_t)(((h * 8 + b) << 10) + s) * 64 + hd] = f2bf(acc[mi][ni][rg] + bv_);
                }
            }
        }
    } else {
        // v transposed: vT[(n*64+hd)*1024 + s]
        #pragma unroll
        for (int mi = 0; mi < 4; ++mi) {
            const int r0 = rowTile + mB + mi * 16 + kq * 4;  // 4-row group never crosses b
            const int b = r0 >> 10, s0 = r0 & 1023;
            #pragma unroll
            for (int ni = 0; ni < 4; ++ni) {
                const int c = colTile + nB + ni * 16 + lm;
                const float bv_ = bias[c];
                const int h = c >> 6, hd = c & 63;
                ushort4 pk;
                pk.x = f2bf(acc[mi][ni][0] + bv_);
                pk.y = f2bf(acc[mi][ni][1] + bv_);
                pk.z = f2bf(acc[mi][ni][2] + bv_);
                pk.w = f2bf(acc[mi][ni][3] + bv_);
                *(ushort4*)&vT[(size_t)((h * 8 + b) * 64 + hd) * 1024 + s0] = pk;
            }
        }
    }
}

// ---------------- K2: scores = q @ k^T, write fp32 heatmap ----------------
// grid (8 tTiles, 8 sTiles, 64 n), block 256
__global__ __launch_bounds__(256) void k_scores(
    const u16* __restrict__ qb, const u16* __restrict__ kb, float* __restrict__ heat)
{
    const int n = blockIdx.z;
    const int tT = blockIdx.x * 128, sT = blockIdx.y * 128;

    __shared__ __align__(16) u16 As[128 * 72];
    __shared__ __align__(16) u16 Bs[128 * 72];

    const int tid = threadIdx.x;
    const int lane = tid & 63, w = tid >> 6;
    const int lm = lane & 15, kq = lane >> 4;
    const int mB = (w >> 1) * 64, nB = (w & 1) * 64;

    const u16* __restrict__ qn = qb + (size_t)n * 65536;
    const u16* __restrict__ kn = kb + (size_t)n * 65536;

    #pragma unroll
    for (int i = 0; i < 4; ++i) {
        int gi = tid + i * 256;
        int r = gi >> 3, c = gi & 7;
        *(bf8*)&As[r * 72 + c * 8] = *(const bf8*)&qn[(size_t)(sT + r) * 64 + c * 8];
        *(bf8*)&Bs[r * 72 + c * 8] = *(const bf8*)&kn[(size_t)(tT + r) * 64 + c * 8];
    }
    __syncthreads();

    f4 acc[4][4] = {};
    #pragma unroll
    for (int ks = 0; ks < 2; ++ks) {
        bf8 a[4], b[4];
        #pragma unroll
        for (int mi = 0; mi < 4; ++mi) a[mi] = *(bf8*)&As[(mB + mi * 16 + lm) * 72 + ks * 32 + kq * 8];
        #pragma unroll
        for (int ni = 0; ni < 4; ++ni) b[ni] = *(bf8*)&Bs[(nB + ni * 16 + lm) * 72 + ks * 32 + kq * 8];
        #pragma unroll
        for (int mi = 0; mi < 4; ++mi)
            #pragma unroll
            for (int ni = 0; ni < 4; ++ni)
                acc[mi][ni] = MFMA16(a[mi], b[ni], acc[mi][ni]);
    }

    float* __restrict__ hp = heat + ((size_t)n << 20);
    #pragma unroll
    for (int mi = 0; mi < 4; ++mi) {
        const int s0 = sT + mB + mi * 16 + kq * 4;
        #pragma unroll
        for (int ni = 0; ni < 4; ++ni) {
            const int t = tT + nB + ni * 16 + lm;
            #pragma unroll
            for (int rg = 0; rg < 4; ++rg)
                hp[(size_t)(s0 + rg) * 1024 + t] = acc[mi][ni][rg];
        }
    }
}

// ---------------- K3: per-row causal softmax stats (m, 1/l) ----------------
__global__ __launch_bounds__(256) void k_stats(const float* __restrict__ heat,
    float* __restrict__ mb, float* __restrict__ lb)
{
    const int row = blockIdx.x * 4 + (threadIdx.x >> 6);
    const int lane = threadIdx.x & 63;
    const int n = row >> 10, s = row & 1023;
    const float* __restrict__ rp = heat + ((size_t)n << 20) + ((size_t)s << 10);

    float mx = -3.0e38f;
    for (int t = lane * 4; t <= s; t += 256) {
        float4 fv = *(const float4*)&rp[t];
        if (t + 0 <= s) mx = fmaxf(mx, fv.x);
        if (t + 1 <= s) mx = fmaxf(mx, fv.y);
        if (t + 2 <= s) mx = fmaxf(mx, fv.z);
        if (t + 3 <= s) mx = fmaxf(mx, fv.w);
    }
    #pragma unroll
    for (int o = 32; o > 0; o >>= 1) mx = fmaxf(mx, __shfl_xor(mx, o));

    float l = 0.f;
    for (int t = lane * 4; t <= s; t += 256) {
        float4 fv = *(const float4*)&rp[t];
        if (t + 0 <= s) l += __expf(fv.x - mx);
        if (t + 1 <= s) l += __expf(fv.y - mx);
        if (t + 2 <= s) l += __expf(fv.z - mx);
        if (t + 3 <= s) l += __expf(fv.w - mx);
    }
    #pragma unroll
    for (int o = 32; o > 0; o >>= 1) l += __shfl_xor(l, o);

    if (lane == 0) { mb[row] = mx; lb[row] = 1.0f / l; }
}

// ---------------- K4: wv = P @ v (MFMA), P built in LDS from heat ----------------
// grid (8 sTiles, 64 n), block 256 (4 waves 2x2 over M=128 x N=64)
__global__ __launch_bounds__(256) void k_pv(
    const float* __restrict__ heat, const u16* __restrict__ vT,
    const float* __restrict__ mb, const float* __restrict__ lb,
    u16* __restrict__ wvb)
{
    const int n = blockIdx.y;
    const int sT = blockIdx.x;
    const int s0 = sT * 128;

    __shared__ __align__(16) u16 Ps[128 * 136];
    __shared__ __align__(16) u16 Vs[64 * 136];

    const int tid = threadIdx.x;
    const int lane = tid & 63, w = tid >> 6;
    const int lm = lane & 15, kq = lane >> 4;
    const int mB = (w >> 1) * 64, nB = (w & 1) * 32;

    const int pr = tid >> 1, ph = (tid & 1) * 64;  // P-gen mapping: row, col-half
    const int srow = s0 + pr;
    const float m_r = mb[(n << 10) + srow];
    const float li_r = lb[(n << 10) + srow];

    const float* __restrict__ hp = heat + ((size_t)n << 20) + (size_t)srow * 1024;
    const u16* __restrict__ vn = vT + (size_t)n * 65536;

    f4 acc[4][2] = {};

    for (int tt = 0; tt <= sT; ++tt) {
        const int t0 = tt * 128;
        __syncthreads();
        // stage V chunk: Vs[v][t'] (64 x 128, stride 136)
        #pragma unroll
        for (int i = 0; i < 4; ++i) {
            int gi = tid + i * 256;
            int r = gi >> 4, g = gi & 15;
            *(bf8*)&Vs[r * 136 + g * 8] = *(const bf8*)&vn[(size_t)r * 1024 + t0 + g * 8];
        }
        // stage P chunk: Ps[s'][t'] = exp(score-m)*linv (bf16), causal-masked
        #pragma unroll
        for (int j = 0; j < 16; ++j) {
            int c = ph + j * 4;
            float4 f = *(const float4*)&hp[t0 + c];
            int t = t0 + c;
            ushort4 pk;
            pk.x = (t + 0 <= srow) ? f2bf(__expf(f.x - m_r) * li_r) : (u16)0;
            pk.y = (t + 1 <= srow) ? f2bf(__expf(f.y - m_r) * li_r) : (u16)0;
            pk.z = (t + 2 <= srow) ? f2bf(__expf(f.z - m_r) * li_r) : (u16)0;
            pk.w = (t + 3 <= srow) ? f2bf(__expf(f.w - m_r) * li_r) : (u16)0;
            *(ushort4*)&Ps[pr * 136 + c] = pk;
        }
        __syncthreads();
        #pragma unroll
        for (int ks = 0; ks < 4; ++ks) {
            bf8 a[4], b[2];
            #pragma unroll
            for (int mi = 0; mi < 4; ++mi) a[mi] = *(bf8*)&Ps[(mB + mi * 16 + lm) * 136 + ks * 32 + kq * 8];
            #pragma unroll
            for (int ni = 0; ni < 2; ++ni) b[ni] = *(bf8*)&Vs[(nB + ni * 16 + lm) * 136 + ks * 32 + kq * 8];
            #pragma unroll
            for (int mi = 0; mi < 4; ++mi)
                #pragma unroll
                for (int ni = 0; ni < 2; ++ni)
                    acc[mi][ni] = MFMA16(a[mi], b[ni], acc[mi][ni]);
        }
    }

    #pragma unroll
    for (int mi = 0; mi < 4; ++mi) {
        const int s = s0 + mB + mi * 16 + kq * 4;
        #pragma unroll
        for (int ni = 0; ni < 2; ++ni) {
            const int v = nB + ni * 16 + lm;
            #pragma unroll
            for (int rg = 0; rg < 4; ++rg)
                wvb[(size_t)((n << 10) + s + rg) * 64 + v] = f2bf(acc[mi][ni][rg]);
        }
    }
}

// ---------------- K5: out = concat_heads(wv) @ Wo + bo ----------------
// grid (4 colTiles, 64 rowTiles), block 256
__global__ __launch_bounds__(256) void k_out(
    const u16* __restrict__ wvb, const u16* __restrict__ WoT, const float* __restrict__ bo,
    float* __restrict__ outp)
{
    const int colTile = blockIdx.x * 128;
    const int rowTile = blockIdx.y * 128;
    const int b = rowTile >> 10, s0 = rowTile & 1023;

    __shared__ __align__(16) u16 As[128 * 72];
    __shared__ __align__(16) u16 Bs[128 * 72];

    const int tid = threadIdx.x;
    const int lane = tid & 63, w = tid >> 6;
    const int lm = lane & 15, kq = lane >> 4;
    const int mB = (w >> 1) * 64, nB = (w & 1) * 64;

    f4 acc[4][4] = {};

    for (int k0 = 0; k0 < 512; k0 += 64) {
        const int h = k0 >> 6;
        const u16* __restrict__ abase = wvb + (size_t)((h * 8 + b) * 1024 + s0) * 64;
        __syncthreads();
        #pragma unroll
        for (int i = 0; i < 4; ++i) {
            int gi = tid + i * 256;
            int r = gi >> 3, c = gi & 7;
            *(bf8*)&As[r * 72 + c * 8] = *(const bf8*)&abase[(size_t)r * 64 + c * 8];
            *(bf8*)&Bs[r * 72 + c * 8] = *(const bf8*)&WoT[(size_t)(colTile + r) * 512 + k0 + c * 8];
        }
        __syncthreads();
        #pragma unroll
        for (int ks = 0; ks < 2; ++ks) {
            bf8 a[4], b2[4];
            #pragma unroll
            for (int mi = 0; mi < 4; ++mi) a[mi] = *(bf8*)&As[(mB + mi * 16 + lm) * 72 + ks * 32 + kq * 8];
            #pragma unroll
            for (int ni = 0; ni < 4; ++ni) b2[ni] = *(bf8*)&Bs[(nB + ni * 16 + lm) * 72 + ks * 32 + kq * 8];
            #pragma unroll
            for (int mi = 0; mi < 4; ++mi)
                #pragma unroll
                for (int ni = 0; ni < 4; ++ni)
                    acc[mi][ni] = MFMA16(a[mi], b2[ni], acc[mi][ni]);
        }
    }

    #pragma unroll
    for (int mi = 0; mi < 4; ++mi) {
        const int r0 = rowTile + mB + mi * 16 + kq * 4;
        #pragma unroll
        for (int ni = 0; ni < 4; ++ni) {
            const int c = colTile + nB + ni * 16 + lm;
            const float bv_ = bo[c];
            #pragma unroll
            for (int rg = 0; rg < 4; ++rg)
                outp[(size_t)(r0 + rg) * 512 + c] = acc[mi][ni][rg] + bv_;
        }
    }
}

extern "C" void kernel_launch(void* const* d_in, const int* in_sizes, int n_in,
                              void* d_out, int out_size, void* d_ws, size_t ws_size,
                              hipStream_t stream)
{
    (void)in_sizes; (void)n_in; (void)out_size; (void)ws_size;

    const float* x  = (const float*)d_in[0];
    const float* Wq = (const float*)d_in[1];
    const float* bq = (const float*)d_in[2];
    const float* Wk = (const float*)d_in[3];
    const float* bk = (const float*)d_in[4];
    const float* Wv = (const float*)d_in[5];
    const float* bv = (const float*)d_in[6];
    const float* Wo = (const float*)d_in[7];
    const float* bo = (const float*)d_in[8];

    float* outp = (float*)d_out;             // [8,1024,512] fp32
    float* heat = outp + 4194304;            // [64,1024,1024] fp32

    u16* ws16 = (u16*)d_ws;
    u16* xb  = ws16;                          // [8192,512] bf16
    u16* WqT = xb  + 4194304;                 // [512,512] bf16 transposed
    u16* WkT = WqT + 262144;
    u16* WvT = WkT + 262144;
    u16* WoT = WvT + 262144;
    u16* qb  = WoT + 262144;                  // [64,1024,64] bf16
    u16* kb  = qb  + 4194304;                 // [64,1024,64] bf16
    u16* vT  = kb  + 4194304;                 // [64,64,1024] bf16 (v transposed)
    u16* wvb = vT  + 4194304;                 // [64,1024,64] bf16
    float* mb = (float*)(wvb + 4194304);      // [65536] fp32
    float* lb = mb + 65536;

    k_cvt_x <<<1024, 256, 0, stream>>>((const float4*)x, (ushort4*)xb);
    k_cvt_wT<<<dim3(8, 8, 4), 256, 0, stream>>>(Wq, Wk, Wv, Wo, WqT, WkT, WvT, WoT);
    k_qkv   <<<dim3(4, 64, 3), 256, 0, stream>>>(xb, WqT, WkT, WvT, bq, bk, bv, qb, kb, vT);
    k_scores<<<dim3(8, 8, 64), 256, 0, stream>>>(qb, kb, heat);
    k_stats <<<16384, 256, 0, stream>>>(heat, mb, lb);
    k_pv    <<<dim3(8, 64), 256, 0, stream>>>(heat, vT, mb, lb, wvb);
    k_out   <<<dim3(4, 64), 256, 0, stream>>>(wvb, WoT, bo, outp);
}

// Round 4
// 395.028 us; speedup vs baseline: 1.9242x; 1.4400x over previous
//
#include <hip/hip_runtime.h>

// GTN_MultiHeadAttention: B=8,S=1024,D=512,H=8,hd=64, N=H*B=64.
// Round 4: fused flash-style attention (scores+softmax+PV in one kernel).
// Heatmap is write-only now (R3's k_pv re-read 470MB of it at 0.9% MfmaUtil).
// MFMA 16x16x32_bf16; layouts: A[m=lane&15][k=quad*8+j], C/D col=lane&15,
// row=quad*4+reg. LDS strides 136/72 u16 (+4-bank row rotation, <=2-way).

typedef unsigned short u16;
typedef unsigned int u32;
typedef __attribute__((ext_vector_type(8))) short bf8;   // 8 bf16 (16B)
typedef __attribute__((ext_vector_type(4))) float f4;

__device__ __forceinline__ u16 f2bf(float f) {
    u32 x = __builtin_bit_cast(u32, f);
    return (u16)((x + 0x7FFFu + ((x >> 16) & 1u)) >> 16);  // RNE
}

#define MFMA16(a, b, c) __builtin_amdgcn_mfma_f32_16x16x32_bf16((a), (b), (c), 0, 0, 0)

// ---------------- cvt: x fp32 -> bf16 ----------------
__global__ __launch_bounds__(256) void k_cvt_x(const float4* __restrict__ xi,
                                               ushort4* __restrict__ xo)
{
    int idx = blockIdx.x * 256 + threadIdx.x;
    for (int i = idx; i < 1048576; i += 262144) {
        float4 f = xi[i];
        ushort4 o;
        o.x = f2bf(f.x); o.y = f2bf(f.y); o.z = f2bf(f.z); o.w = f2bf(f.w);
        xo[i] = o;
    }
}

// ---------------- cvt: W fp32 [k][c] -> bf16 transposed [c][k] ----------------
__global__ __launch_bounds__(256) void k_cvt_wT(
    const float* __restrict__ Wq, const float* __restrict__ Wk,
    const float* __restrict__ Wv, const float* __restrict__ Wo,
    u16* __restrict__ WqT, u16* __restrict__ WkT,
    u16* __restrict__ WvT, u16* __restrict__ WoT)
{
    const int z = blockIdx.z;
    const float* __restrict__ W = (z == 0) ? Wq : (z == 1) ? Wk : (z == 2) ? Wv : Wo;
    u16* __restrict__ WT        = (z == 0) ? WqT : (z == 1) ? WkT : (z == 2) ? WvT : WoT;

    __shared__ __align__(16) u16 Ts[64 * 72];
    const int k0 = blockIdx.x * 64, c0 = blockIdx.y * 64;
    const int tid = threadIdx.x;
    const int r = tid >> 4, cc = (tid & 15) * 4;
    #pragma unroll
    for (int rr = r; rr < 64; rr += 16) {
        float4 f = *(const float4*)&W[(size_t)(k0 + rr) * 512 + c0 + cc];
        Ts[(cc + 0) * 72 + rr] = f2bf(f.x);
        Ts[(cc + 1) * 72 + rr] = f2bf(f.y);
        Ts[(cc + 2) * 72 + rr] = f2bf(f.z);
        Ts[(cc + 3) * 72 + rr] = f2bf(f.w);
    }
    __syncthreads();
    #pragma unroll
    for (int i = 0; i < 2; ++i) {
        int gi = tid + i * 256;
        int cr = gi >> 3, g = gi & 7;
        bf8 v = *(bf8*)&Ts[cr * 72 + g * 8];
        *(bf8*)&WT[(size_t)(c0 + cr) * 512 + k0 + g * 8] = v;
    }
}

// ---------------- K1: QKV projection, MFMA ----------------
// grid (4 colTiles, 64 rowTiles, 3 weights), block 256 (4 waves, 2x2)
__global__ __launch_bounds__(256) void k_qkv(
    const u16* __restrict__ xb,
    const u16* __restrict__ WqT, const u16* __restrict__ WkT, const u16* __restrict__ WvT,
    const float* __restrict__ bq, const float* __restrict__ bk, const float* __restrict__ bv,
    u16* __restrict__ qb, u16* __restrict__ kb, u16* __restrict__ vT)
{
    const int which = blockIdx.z;
    const u16* __restrict__ WT     = (which == 0) ? WqT : (which == 1) ? WkT : WvT;
    const float* __restrict__ bias = (which == 0) ? bq : (which == 1) ? bk : bv;

    const int colTile = blockIdx.x * 128;
    const int rowTile = blockIdx.y * 128;

    __shared__ __align__(16) u16 As[128 * 72];
    __shared__ __align__(16) u16 Bs[128 * 72];

    const int tid = threadIdx.x;
    const int lane = tid & 63, w = tid >> 6;
    const int lm = lane & 15, kq = lane >> 4;
    const int mB = (w >> 1) * 64, nB = (w & 1) * 64;

    f4 acc[4][4] = {};

    for (int k0 = 0; k0 < 512; k0 += 64) {
        __syncthreads();
        #pragma unroll
        for (int i = 0; i < 4; ++i) {
            int gi = tid + i * 256;
            int r = gi >> 3, c = gi & 7;
            *(bf8*)&As[r * 72 + c * 8] = *(const bf8*)&xb[(size_t)(rowTile + r) * 512 + k0 + c * 8];
            *(bf8*)&Bs[r * 72 + c * 8] = *(const bf8*)&WT[(size_t)(colTile + r) * 512 + k0 + c * 8];
        }
        __syncthreads();
        #pragma unroll
        for (int ks = 0; ks < 2; ++ks) {
            bf8 a[4], b[4];
            #pragma unroll
            for (int mi = 0; mi < 4; ++mi) a[mi] = *(bf8*)&As[(mB + mi * 16 + lm) * 72 + ks * 32 + kq * 8];
            #pragma unroll
            for (int ni = 0; ni < 4; ++ni) b[ni] = *(bf8*)&Bs[(nB + ni * 16 + lm) * 72 + ks * 32 + kq * 8];
            #pragma unroll
            for (int mi = 0; mi < 4; ++mi)
                #pragma unroll
                for (int ni = 0; ni < 4; ++ni)
                    acc[mi][ni] = MFMA16(a[mi], b[ni], acc[mi][ni]);
        }
    }

    if (which < 2) {
        u16* __restrict__ outp = (which == 0) ? qb : kb;
        #pragma unroll
        for (int mi = 0; mi < 4; ++mi) {
            const int r0 = rowTile + mB + mi * 16 + kq * 4;
            #pragma unroll
            for (int ni = 0; ni < 4; ++ni) {
                const int c = colTile + nB + ni * 16 + lm;
                const float bv_ = bias[c];
                const int h = c >> 6, hd = c & 63;
                #pragma unroll
                for (int rg = 0; rg < 4; ++rg) {
                    const int rr = r0 + rg;
                    const int b = rr >> 10, s = rr & 1023;
                    outp[(size_t)(((h * 8 + b) << 10) + s) * 64 + hd] = f2bf(acc[mi][ni][rg] + bv_);
                }
            }
        }
    } else {
        // v transposed: vT[(n*64+hd)*1024 + s]
        #pragma unroll
        for (int mi = 0; mi < 4; ++mi) {
            const int r0 = rowTile + mB + mi * 16 + kq * 4;  // 4-row group never crosses b
            const int b = r0 >> 10, s0 = r0 & 1023;
            #pragma unroll
            for (int ni = 0; ni < 4; ++ni) {
                const int c = colTile + nB + ni * 16 + lm;
                const float bv_ = bias[c];
                const int h = c >> 6, hd = c & 63;
                ushort4 pk;
                pk.x = f2bf(acc[mi][ni][0] + bv_);
                pk.y = f2bf(acc[mi][ni][1] + bv_);
                pk.z = f2bf(acc[mi][ni][2] + bv_);
                pk.w = f2bf(acc[mi][ni][3] + bv_);
                *(ushort4*)&vT[(size_t)((h * 8 + b) * 64 + hd) * 1024 + s0] = pk;
            }
        }
    }
}

// ---------------- K2: fused flash attention ----------------
// grid (64 n, 8 sTiles), block 256 = 4 waves, each wave 32 rows x 128 cols.
// Loops ALL 8 t-tiles: S via MFMA -> raw heat write (full matrix, as required);
// causal tiles additionally: online softmax in C-layout regs, P bf16 -> LDS
// (reusing k-tile region), PV MFMA into O accumulator.
__global__ __launch_bounds__(256) void k_attn(
    const u16* __restrict__ qb, const u16* __restrict__ kb, const u16* __restrict__ vT,
    float* __restrict__ heat, u16* __restrict__ wvb)
{
    const int n = blockIdx.x;
    const int sT = blockIdx.y;
    const int s0 = sT * 128;

    __shared__ __align__(16) u16 KPs[128 * 136];  // k-tile, then P-tile (union)
    __shared__ __align__(16) u16 Vs[64 * 136];    // v^T tile [v][t]

    const int tid = threadIdx.x;
    const int lane = tid & 63, w = tid >> 6;
    const int lm = lane & 15, kq = lane >> 4;
    const int mB = w * 32;

    const u16* __restrict__ qn = qb + (size_t)n * 65536;
    const u16* __restrict__ kn = kb + (size_t)n * 65536;
    const u16* __restrict__ vn = vT + (size_t)n * 65536;
    float* __restrict__ hp = heat + ((size_t)n << 20);

    // persistent q A-frags: rows s0+mB+mi*16+lm, k = ks*32+kq*8
    bf8 aq[2][2];
    #pragma unroll
    for (int mi = 0; mi < 2; ++mi)
        #pragma unroll
        for (int ks = 0; ks < 2; ++ks)
            aq[mi][ks] = *(const bf8*)&qn[(size_t)(s0 + mB + mi * 16 + lm) * 64 + ks * 32 + kq * 8];

    f4 accO[2][4] = {};
    float m_i[2][4], l_i[2][4];
    #pragma unroll
    for (int mi = 0; mi < 2; ++mi)
        #pragma unroll
        for (int rg = 0; rg < 4; ++rg) { m_i[mi][rg] = -3.0e38f; l_i[mi][rg] = 0.f; }

    for (int tt = 0; tt < 8; ++tt) {
        const int t0 = tt * 128;
        const bool causal = (tt <= sT);

        __syncthreads();  // prev-iter KPs(P)/Vs reads done before restage
        #pragma unroll
        for (int i = 0; i < 4; ++i) {
            int gi = tid + i * 256;
            int r = gi >> 3, c = gi & 7;
            *(bf8*)&KPs[r * 136 + c * 8] = *(const bf8*)&kn[(size_t)(t0 + r) * 64 + c * 8];
        }
        if (causal) {
            #pragma unroll
            for (int i = 0; i < 4; ++i) {
                int gi = tid + i * 256;
                int r = gi >> 4, g = gi & 15;
                *(bf8*)&Vs[r * 136 + g * 8] = *(const bf8*)&vn[(size_t)r * 1024 + t0 + g * 8];
            }
        }
        __syncthreads();

        // S = q @ k^T for this 128x128 tile
        f4 accS[2][8] = {};
        #pragma unroll
        for (int ks = 0; ks < 2; ++ks) {
            bf8 b[8];
            #pragma unroll
            for (int ni = 0; ni < 8; ++ni) b[ni] = *(bf8*)&KPs[(ni * 16 + lm) * 136 + ks * 32 + kq * 8];
            #pragma unroll
            for (int mi = 0; mi < 2; ++mi)
                #pragma unroll
                for (int ni = 0; ni < 8; ++ni)
                    accS[mi][ni] = MFMA16(aq[mi][ks], b[ni], accS[mi][ni]);
        }

        // raw heatmap write (unmasked, full matrix)
        #pragma unroll
        for (int mi = 0; mi < 2; ++mi) {
            #pragma unroll
            for (int rg = 0; rg < 4; ++rg) {
                float* rowp = &hp[(size_t)(s0 + mB + mi * 16 + kq * 4 + rg) * 1024 + t0 + lm];
                #pragma unroll
                for (int ni = 0; ni < 8; ++ni) rowp[ni * 16] = accS[mi][ni][rg];
            }
        }

        if (causal) {
            __syncthreads();  // all waves done reading k from KPs before P overwrite
            const bool diag = (tt == sT);
            #pragma unroll
            for (int mi = 0; mi < 2; ++mi) {
                #pragma unroll
                for (int rg = 0; rg < 4; ++rg) {
                    const int srow = s0 + mB + mi * 16 + kq * 4 + rg;
                    float tm = -3.0e38f;
                    #pragma unroll
                    for (int ni = 0; ni < 8; ++ni) {
                        float sv = accS[mi][ni][rg];
                        if (diag && (t0 + ni * 16 + lm > srow)) sv = -3.0e38f;
                        tm = fmaxf(tm, sv);
                    }
                    tm = fmaxf(tm, __shfl_xor(tm, 1));
                    tm = fmaxf(tm, __shfl_xor(tm, 2));
                    tm = fmaxf(tm, __shfl_xor(tm, 4));
                    tm = fmaxf(tm, __shfl_xor(tm, 8));
                    const float mn = fmaxf(m_i[mi][rg], tm);
                    const float alpha = __expf(m_i[mi][rg] - mn);
                    float rs = 0.f;
                    #pragma unroll
                    for (int ni = 0; ni < 8; ++ni) {
                        float sv = accS[mi][ni][rg];
                        const bool ok = !diag || (t0 + ni * 16 + lm <= srow);
                        float p = ok ? __expf(sv - mn) : 0.f;
                        rs += p;
                        KPs[(mB + mi * 16 + kq * 4 + rg) * 136 + ni * 16 + lm] = f2bf(p);
                    }
                    rs += __shfl_xor(rs, 1);
                    rs += __shfl_xor(rs, 2);
                    rs += __shfl_xor(rs, 4);
                    rs += __shfl_xor(rs, 8);
                    l_i[mi][rg] = l_i[mi][rg] * alpha + rs;
                    m_i[mi][rg] = mn;
                    #pragma unroll
                    for (int vni = 0; vni < 4; ++vni) accO[mi][vni][rg] *= alpha;
                }
            }
            __syncthreads();  // P visible to A-frag reads (cross-lane)

            // O += P @ V   (A = P from KPs[s][t], B = V from Vs[v][t])
            #pragma unroll
            for (int ks = 0; ks < 4; ++ks) {
                bf8 a[2], b[4];
                #pragma unroll
                for (int mi = 0; mi < 2; ++mi) a[mi] = *(bf8*)&KPs[(mB + mi * 16 + lm) * 136 + ks * 32 + kq * 8];
                #pragma unroll
                for (int vni = 0; vni < 4; ++vni) b[vni] = *(bf8*)&Vs[(vni * 16 + lm) * 136 + ks * 32 + kq * 8];
                #pragma unroll
                for (int mi = 0; mi < 2; ++mi)
                    #pragma unroll
                    for (int vni = 0; vni < 4; ++vni)
                        accO[mi][vni] = MFMA16(a[mi], b[vni], accO[mi][vni]);
            }
        }
    }

    // finalize: O /= l, write wv bf16 [n][s][64]
    u16* __restrict__ wn = wvb + (size_t)n * 65536;
    #pragma unroll
    for (int mi = 0; mi < 2; ++mi) {
        #pragma unroll
        for (int rg = 0; rg < 4; ++rg) {
            const float li = 1.0f / l_i[mi][rg];
            const int s = s0 + mB + mi * 16 + kq * 4 + rg;
            #pragma unroll
            for (int vni = 0; vni < 4; ++vni)
                wn[(size_t)s * 64 + vni * 16 + lm] = f2bf(accO[mi][vni][rg] * li);
        }
    }
}

// ---------------- K5: out = concat_heads(wv) @ Wo + bo ----------------
// grid (4 colTiles, 64 rowTiles), block 256
__global__ __launch_bounds__(256) void k_out(
    const u16* __restrict__ wvb, const u16* __restrict__ WoT, const float* __restrict__ bo,
    float* __restrict__ outp)
{
    const int colTile = blockIdx.x * 128;
    const int rowTile = blockIdx.y * 128;
    const int b = rowTile >> 10, s0 = rowTile & 1023;

    __shared__ __align__(16) u16 As[128 * 72];
    __shared__ __align__(16) u16 Bs[128 * 72];

    const int tid = threadIdx.x;
    const int lane = tid & 63, w = tid >> 6;
    const int lm = lane & 15, kq = lane >> 4;
    const int mB = (w >> 1) * 64, nB = (w & 1) * 64;

    f4 acc[4][4] = {};

    for (int k0 = 0; k0 < 512; k0 += 64) {
        const int h = k0 >> 6;
        const u16* __restrict__ abase = wvb + (size_t)((h * 8 + b) * 1024 + s0) * 64;
        __syncthreads();
        #pragma unroll
        for (int i = 0; i < 4; ++i) {
            int gi = tid + i * 256;
            int r = gi >> 3, c = gi & 7;
            *(bf8*)&As[r * 72 + c * 8] = *(const bf8*)&abase[(size_t)r * 64 + c * 8];
            *(bf8*)&Bs[r * 72 + c * 8] = *(const bf8*)&WoT[(size_t)(colTile + r) * 512 + k0 + c * 8];
        }
        __syncthreads();
        #pragma unroll
        for (int ks = 0; ks < 2; ++ks) {
            bf8 a[4], b2[4];
            #pragma unroll
            for (int mi = 0; mi < 4; ++mi) a[mi] = *(bf8*)&As[(mB + mi * 16 + lm) * 72 + ks * 32 + kq * 8];
            #pragma unroll
            for (int ni = 0; ni < 4; ++ni) b2[ni] = *(bf8*)&Bs[(nB + ni * 16 + lm) * 72 + ks * 32 + kq * 8];
            #pragma unroll
            for (int mi = 0; mi < 4; ++mi)
                #pragma unroll
                for (int ni = 0; ni < 4; ++ni)
                    acc[mi][ni] = MFMA16(a[mi], b2[ni], acc[mi][ni]);
        }
    }

    #pragma unroll
    for (int mi = 0; mi < 4; ++mi) {
        const int r0 = rowTile + mB + mi * 16 + kq * 4;
        #pragma unroll
        for (int ni = 0; ni < 4; ++ni) {
            const int c = colTile + nB + ni * 16 + lm;
            const float bv_ = bo[c];
            #pragma unroll
            for (int rg = 0; rg < 4; ++rg)
                outp[(size_t)(r0 + rg) * 512 + c] = acc[mi][ni][rg] + bv_;
        }
    }
}

extern "C" void kernel_launch(void* const* d_in, const int* in_sizes, int n_in,
                              void* d_out, int out_size, void* d_ws, size_t ws_size,
                              hipStream_t stream)
{
    (void)in_sizes; (void)n_in; (void)out_size; (void)ws_size;

    const float* x  = (const float*)d_in[0];
    const float* Wq = (const float*)d_in[1];
    const float* bq = (const float*)d_in[2];
    const float* Wk = (const float*)d_in[3];
    const float* bk = (const float*)d_in[4];
    const float* Wv = (const float*)d_in[5];
    const float* bv = (const float*)d_in[6];
    const float* Wo = (const float*)d_in[7];
    const float* bo = (const float*)d_in[8];

    float* outp = (float*)d_out;             // [8,1024,512] fp32
    float* heat = outp + 4194304;            // [64,1024,1024] fp32

    u16* ws16 = (u16*)d_ws;
    u16* xb  = ws16;                          // [8192,512] bf16
    u16* WqT = xb  + 4194304;                 // [512,512] bf16 transposed
    u16* WkT = WqT + 262144;
    u16* WvT = WkT + 262144;
    u16* WoT = WvT + 262144;
    u16* qb  = WoT + 262144;                  // [64,1024,64] bf16
    u16* kb  = qb  + 4194304;                 // [64,1024,64] bf16
    u16* vT  = kb  + 4194304;                 // [64,64,1024] bf16 (v transposed)
    u16* wvb = vT  + 4194304;                 // [64,1024,64] bf16

    k_cvt_x <<<1024, 256, 0, stream>>>((const float4*)x, (ushort4*)xb);
    k_cvt_wT<<<dim3(8, 8, 4), 256, 0, stream>>>(Wq, Wk, Wv, Wo, WqT, WkT, WvT, WoT);
    k_qkv   <<<dim3(4, 64, 3), 256, 0, stream>>>(xb, WqT, WkT, WvT, bq, bk, bv, qb, kb, vT);
    k_attn  <<<dim3(64, 8), 256, 0, stream>>>(qb, kb, vT, heat, wvb);
    k_out   <<<dim3(4, 64), 256, 0, stream>>>(wvb, WoT, bo, outp);
}